// Round 3
// baseline (17698.952 us; speedup 1.0000x reference)
//
#include <hip/hip_runtime.h>
#include <hip/hip_bf16.h>

// FF_27650999451977: 2-layer gated RNN (MGU), SEQ=512, B=64, H=IN=512.
// I/O is FP32 (per reference dtype). Compute: bf16 MFMA, fp32 accumulate,
// fp32 hidden state. Persistent cooperative kernel, flag-based pipeline sync,
// ring-buffered layer-0 history (ws 1.3 MB).

#define SEQn 512
#define Bn   64
#define Hn   512
#define RING 8    // layer-0 h-history ring depth (back-pressured)

typedef __bf16 bf16x8 __attribute__((ext_vector_type(8)));
typedef float  f32x4  __attribute__((ext_vector_type(4)));

// counter index: [layer][t][mg] -> 64B-padded lines (16 ints)
__device__ __forceinline__ int cidx(int l, int t, int mg) {
    return ((((l << 9) | t) << 2) | mg) << 4;
}

__device__ __forceinline__ void spin_until(const int* p, int target) {
    while (__hip_atomic_load(p, __ATOMIC_RELAXED, __HIP_MEMORY_SCOPE_AGENT) < target)
        __builtin_amdgcn_s_sleep(2);
}

__device__ __forceinline__ bf16x8 cvt8(const float* p) {
    bf16x8 r;
#pragma unroll
    for (int i = 0; i < 8; ++i) r[i] = (__bf16)p[i];
    return r;
}

__global__ void __launch_bounds__(256, 1)
rnn_persistent(const float* __restrict__ x,
               const float* __restrict__ Wjx, const float* __restrict__ bjx,
               const float* __restrict__ Wjh, const float* __restrict__ bjh,
               const float* __restrict__ Wkx, const float* __restrict__ bkx,
               const float* __restrict__ Wkh, const float* __restrict__ bkh,
               float* __restrict__ out,       // [SEQ][B][H] outputs, then [2][B][H] hidden
               float* __restrict__ ring,      // ws: [RING][B][H] layer-0 h history ring
               int* __restrict__ ctr)         // ws: counters
{
    const int wg    = blockIdx.x;
    const int layer = wg >> 7;       // 0..1
    const int id    = wg & 127;
    const int mg    = id >> 5;       // 0..3  (16 batch rows each)
    const int ng    = id & 31;       // 0..31 (16 output units each)
    const int tid   = threadIdx.x;
    const int wave  = tid >> 6;      // 0..3  (K-split: waves 0,1 = x-side, 2,3 = h-side)
    const int lane  = tid & 63;

    // ---- stationary weights -> bf16 VGPR frags (B-operand: col = lane&15) ----
    const int ucol = ng * 16 + (lane & 15);
    const int koff = (wave & 1) * 256 + ((lane >> 4) << 3);  // k offset within 512-half
    const float* wjsrc = ((wave < 2) ? Wjx : Wjh) + (size_t)layer * Hn * Hn + (size_t)ucol * Hn + koff;
    const float* wksrc = ((wave < 2) ? Wkx : Wkh) + (size_t)layer * Hn * Hn + (size_t)ucol * Hn + koff;
    bf16x8 wj[8], wk[8];
#pragma unroll
    for (int kt = 0; kt < 8; ++kt) {
        wj[kt] = cvt8(wjsrc + kt * 32);
        wk[kt] = cvt8(wksrc + kt * 32);
    }

    // ---- epilogue constants: thread tid -> output (row ml, unit nu) ----
    const int ml = tid >> 4;             // 0..15
    const int nu = tid & 15;             // 0..15
    const int ue = ng * 16 + nu;         // global unit
    const int be = mg * 16 + ml;         // global batch row
    const float bje = bjx[layer * Hn + ue] + bjh[layer * Hn + ue];
    const float bke = bkx[layer * Hn + ue] + bkh[layer * Hn + ue];

    __shared__ float part[4][2][16][16];  // [wave][j/k][row][col]

    const int m = mg * 16 + (lane & 15);  // A row (batch) for MFMA fragments

    auto compute_store = [&](const float* Abase) {
        f32x4 aj = {0.f, 0.f, 0.f, 0.f}, ak = {0.f, 0.f, 0.f, 0.f};
        const float* arow = Abase + (size_t)m * Hn + koff;
#pragma unroll
        for (int kt = 0; kt < 8; ++kt) {
            bf16x8 af = cvt8(arow + kt * 32);
            aj = __builtin_amdgcn_mfma_f32_16x16x32_bf16(af, wj[kt], aj, 0, 0, 0);
            ak = __builtin_amdgcn_mfma_f32_16x16x32_bf16(af, wk[kt], ak, 0, 0, 0);
        }
#pragma unroll
        for (int r = 0; r < 4; ++r) {
            part[wave][0][((lane >> 4) << 2) + r][lane & 15] = aj[r];
            part[wave][1][((lane >> 4) << 2) + r][lane & 15] = ak[r];
        }
    };
    auto zero_store = [&]() {
#pragma unroll
        for (int r = 0; r < 4; ++r) {
            part[wave][0][((lane >> 4) << 2) + r][lane & 15] = 0.f;
            part[wave][1][((lane >> 4) << 2) + r][lane & 15] = 0.f;
        }
    };

    for (int t = 0; t < SEQn; ++t) {
        const int slot  = t & (RING - 1);
        const int pslot = (t - 1) & (RING - 1);
        const float *Ax, *Ah;
        float* hc;
        if (layer == 0) {
            Ax = x + (size_t)t * Bn * Hn;
            Ah = ring + (size_t)pslot * Bn * Hn;                   // valid only if t>0
            hc = ring + (size_t)slot * Bn * Hn;
        } else {
            Ax = ring + (size_t)slot * Bn * Hn;                    // layer-0 output, step t
            Ah = (t > 0) ? (out + (size_t)(t - 1) * Bn * Hn) : out; // deref'd only if t>0
            hc = out + (size_t)t * Bn * Hn;
        }

        // layer-0 x-side waves depend only on static input: compute before waiting
        const bool pre = (layer == 0) && (wave < 2);
        if (pre) compute_store(Ax);

        if (tid == 0) {
            if (layer == 0) {
                if (t > 0)     spin_until(ctr + cidx(0, t - 1, mg), 32);
                if (t >= RING) spin_until(ctr + cidx(1, t - RING, mg), 32);  // ring back-pressure
            } else {
                spin_until(ctr + cidx(0, t, mg), 32);
                if (t > 0) spin_until(ctr + cidx(1, t - 1, mg), 32);
            }
        }
        __syncthreads();
        __builtin_amdgcn_fence(__ATOMIC_ACQUIRE, "agent");

        if (!pre) {
            if (wave < 2)      compute_store(Ax);
            else if (t > 0)    compute_store(Ah);
            else               zero_store();
        }
        __syncthreads();

        // ---- epilogue: reduce K-split partials, gates, h update ----
        float sj = part[0][0][ml][nu] + part[1][0][ml][nu] +
                   part[2][0][ml][nu] + part[3][0][ml][nu] + bje;
        float sk = part[0][1][ml][nu] + part[1][1][ml][nu] +
                   part[2][1][ml][nu] + part[3][1][ml][nu] + bke;
        float jj = 1.f / (1.f + __expf(-sj));
        float kk = 1.f / (1.f + __expf(-sk));
        float hprev = (t > 0) ? Ah[(size_t)be * Hn + ue] : 0.f;
        float hnew = jj * (1.f - hprev) + (1.f - kk) * hprev;

        hc[(size_t)be * Hn + ue] = hnew;
        if (t == SEQn - 1)
            out[(size_t)SEQn * Bn * Hn + (size_t)layer * Bn * Hn + (size_t)be * Hn + ue] = hnew;

        __threadfence();
        __syncthreads();
        if (tid == 0) atomicAdd(ctr + cidx(layer, t, mg), 1);
    }
}

extern "C" void kernel_launch(void* const* d_in, const int* in_sizes, int n_in,
                              void* d_out, int out_size, void* d_ws, size_t ws_size,
                              hipStream_t stream) {
    (void)in_sizes; (void)n_in; (void)out_size; (void)ws_size;

    const float* x   = (const float*)d_in[0];
    const float* Wjx = (const float*)d_in[1];
    const float* bjx = (const float*)d_in[2];
    const float* Wjh = (const float*)d_in[3];
    const float* bjh = (const float*)d_in[4];
    const float* Wkx = (const float*)d_in[5];
    const float* bkx = (const float*)d_in[6];
    const float* Wkh = (const float*)d_in[7];
    const float* bkh = (const float*)d_in[8];
    float* out = (float*)d_out;

    char* ws = (char*)d_ws;
    float* ring = (float*)ws;                    // RING*B*H*4 = 1,048,576 B
    int*   ctr  = (int*)(ws + 1048576);          // 2*512*4 lines * 64 B = 262,144 B

    hipMemsetAsync(ctr, 0, 262144, stream);

    void* args[] = { (void*)&x, (void*)&Wjx, (void*)&bjx, (void*)&Wjh, (void*)&bjh,
                     (void*)&Wkx, (void*)&bkx, (void*)&Wkh, (void*)&bkh,
                     (void*)&out, (void*)&ring, (void*)&ctr };
    hipLaunchCooperativeKernel((void*)rnn_persistent, dim3(256), dim3(256),
                               args, 0, stream);
}

// Round 4
// 6194.944 us; speedup vs baseline: 2.8570x; 2.8570x over previous
//
#include <hip/hip_runtime.h>
#include <hip/hip_bf16.h>

// FF_27650999451977: 2-layer gated RNN (MGU), SEQ=512, B=64, H=IN=512, FP32 I/O.
// Persistent cooperative kernel, flag-based pipeline sync.
// Round-4 change: FENCE-FREE producer path. h values are written with
// agent-scope relaxed atomic stores (write-through to LLC), ordered before the
// counter atomicAdd by the vmcnt(0) drain that __syncthreads performs.
// __threadfence() (which emitted a full L2 writeback per wave per step) is gone.
// Consumer side keeps one cheap acquire fence (buffer_inv) after the spin.

#define SEQn 512
#define Bn   64
#define Hn   512
#define RING 8    // layer-0 h-history ring depth (back-pressured)

typedef __bf16 bf16x8 __attribute__((ext_vector_type(8)));
typedef float  f32x4  __attribute__((ext_vector_type(4)));

// counter index: [layer][t][mg] -> 64B-padded lines (16 ints)
__device__ __forceinline__ int cidx(int l, int t, int mg) {
    return ((((l << 9) | t) << 2) | mg) << 4;
}

__device__ __forceinline__ void spin_until(const int* p, int target) {
    while (__hip_atomic_load(p, __ATOMIC_RELAXED, __HIP_MEMORY_SCOPE_AGENT) < target)
        __builtin_amdgcn_s_sleep(1);
}

__device__ __forceinline__ bf16x8 cvt8(const float* p) {
    bf16x8 r;
#pragma unroll
    for (int i = 0; i < 8; ++i) r[i] = (__bf16)p[i];
    return r;
}

__global__ void __launch_bounds__(256, 1)
rnn_persistent(const float* __restrict__ x,
               const float* __restrict__ Wjx, const float* __restrict__ bjx,
               const float* __restrict__ Wjh, const float* __restrict__ bjh,
               const float* __restrict__ Wkx, const float* __restrict__ bkx,
               const float* __restrict__ Wkh, const float* __restrict__ bkh,
               float* __restrict__ out,       // [SEQ][B][H] outputs, then [2][B][H] hidden
               float* __restrict__ ring,      // ws: [RING][B][H] layer-0 h history ring
               int* __restrict__ ctr)         // ws: counters
{
    const int wg    = blockIdx.x;
    const int layer = wg >> 7;       // 0..1
    const int id    = wg & 127;
    const int mg    = id >> 5;       // 0..3  (16 batch rows each)
    const int ng    = id & 31;       // 0..31 (16 output units each)
    const int tid   = threadIdx.x;
    const int wave  = tid >> 6;      // 0..3  (K-split: waves 0,1 = x-side, 2,3 = h-side)
    const int lane  = tid & 63;

    // ---- stationary weights -> bf16 VGPR frags (B-operand: col = lane&15) ----
    const int ucol = ng * 16 + (lane & 15);
    const int koff = (wave & 1) * 256 + ((lane >> 4) << 3);  // k offset within 512-half
    const float* wjsrc = ((wave < 2) ? Wjx : Wjh) + (size_t)layer * Hn * Hn + (size_t)ucol * Hn + koff;
    const float* wksrc = ((wave < 2) ? Wkx : Wkh) + (size_t)layer * Hn * Hn + (size_t)ucol * Hn + koff;
    bf16x8 wj[8], wk[8];
#pragma unroll
    for (int kt = 0; kt < 8; ++kt) {
        wj[kt] = cvt8(wjsrc + kt * 32);
        wk[kt] = cvt8(wksrc + kt * 32);
    }

    // ---- epilogue constants: thread tid -> output (row ml, unit nu) ----
    const int ml = tid >> 4;             // 0..15
    const int nu = tid & 15;             // 0..15
    const int ue = ng * 16 + nu;         // global unit
    const int be = mg * 16 + ml;         // global batch row
    const float bje = bjx[layer * Hn + ue] + bjh[layer * Hn + ue];
    const float bke = bkx[layer * Hn + ue] + bkh[layer * Hn + ue];

    __shared__ float part[4][2][16][16];  // [wave][j/k][row][col]

    const int m = mg * 16 + (lane & 15);  // A row (batch) for MFMA fragments

    auto compute_store = [&](const float* Abase) {
        f32x4 aj = {0.f, 0.f, 0.f, 0.f}, ak = {0.f, 0.f, 0.f, 0.f};
        const float* arow = Abase + (size_t)m * Hn + koff;
#pragma unroll
        for (int kt = 0; kt < 8; ++kt) {
            bf16x8 af = cvt8(arow + kt * 32);
            aj = __builtin_amdgcn_mfma_f32_16x16x32_bf16(af, wj[kt], aj, 0, 0, 0);
            ak = __builtin_amdgcn_mfma_f32_16x16x32_bf16(af, wk[kt], ak, 0, 0, 0);
        }
#pragma unroll
        for (int r = 0; r < 4; ++r) {
            part[wave][0][((lane >> 4) << 2) + r][lane & 15] = aj[r];
            part[wave][1][((lane >> 4) << 2) + r][lane & 15] = ak[r];
        }
    };
    auto zero_store = [&]() {
#pragma unroll
        for (int r = 0; r < 4; ++r) {
            part[wave][0][((lane >> 4) << 2) + r][lane & 15] = 0.f;
            part[wave][1][((lane >> 4) << 2) + r][lane & 15] = 0.f;
        }
    };

    for (int t = 0; t < SEQn; ++t) {
        const int slot  = t & (RING - 1);
        const int pslot = (t - 1) & (RING - 1);
        const float *Ax, *Ah;
        float* hc;
        if (layer == 0) {
            Ax = x + (size_t)t * Bn * Hn;
            Ah = ring + (size_t)pslot * Bn * Hn;                    // valid only if t>0
            hc = ring + (size_t)slot * Bn * Hn;
        } else {
            Ax = ring + (size_t)slot * Bn * Hn;                     // layer-0 output, step t
            Ah = (t > 0) ? (out + (size_t)(t - 1) * Bn * Hn) : out; // deref'd only if t>0
            hc = out + (size_t)t * Bn * Hn;
        }

        // layer-0 x-side waves depend only on static input: compute before waiting
        const bool pre = (layer == 0) && (wave < 2);
        if (pre) compute_store(Ax);

        if (tid == 0) {
            if (layer == 0) {
                if (t > 0)     spin_until(ctr + cidx(0, t - 1, mg), 32);
                if (t >= RING) spin_until(ctr + cidx(1, t - RING, mg), 32);  // ring back-pressure
            } else {
                spin_until(ctr + cidx(0, t, mg), 32);
                if (t > 0) spin_until(ctr + cidx(1, t - 1, mg), 32);
            }
        }
        __syncthreads();
        // cheap acquire: invalidate stale L1/L2 lines so plain loads see the
        // producers' write-through (LLC-coherent) data. No writeback involved.
        __builtin_amdgcn_fence(__ATOMIC_ACQUIRE, "agent");

        if (!pre) {
            if (wave < 2)      compute_store(Ax);
            else if (t > 0)    compute_store(Ah);
            else               zero_store();
        }
        __syncthreads();

        // ---- epilogue: reduce K-split partials, gates, h update ----
        float sj = part[0][0][ml][nu] + part[1][0][ml][nu] +
                   part[2][0][ml][nu] + part[3][0][ml][nu] + bje;
        float sk = part[0][1][ml][nu] + part[1][1][ml][nu] +
                   part[2][1][ml][nu] + part[3][1][ml][nu] + bke;
        float jj = 1.f / (1.f + __expf(-sj));
        float kk = 1.f / (1.f + __expf(-sk));
        float hprev = (t > 0) ? Ah[(size_t)be * Hn + ue] : 0.f;
        float hnew = jj * (1.f - hprev) + (1.f - kk) * hprev;

        // write-through to the coherence point (LLC): no fence needed later.
        __hip_atomic_store(hc + (size_t)be * Hn + ue, hnew,
                           __ATOMIC_RELAXED, __HIP_MEMORY_SCOPE_AGENT);
        if (t == SEQn - 1)
            out[(size_t)SEQn * Bn * Hn + (size_t)layer * Bn * Hn + (size_t)be * Hn + ue] = hnew;

        // __syncthreads drains every thread's vmcnt (compiler emits
        // s_waitcnt vmcnt(0) before s_barrier), so all h stores above are at
        // the LLC before tid 0 publishes the counter. No threadfence.
        __syncthreads();
        if (tid == 0)
            __hip_atomic_fetch_add(ctr + cidx(layer, t, mg), 1,
                                   __ATOMIC_RELAXED, __HIP_MEMORY_SCOPE_AGENT);
    }
}

extern "C" void kernel_launch(void* const* d_in, const int* in_sizes, int n_in,
                              void* d_out, int out_size, void* d_ws, size_t ws_size,
                              hipStream_t stream) {
    (void)in_sizes; (void)n_in; (void)out_size; (void)ws_size;

    const float* x   = (const float*)d_in[0];
    const float* Wjx = (const float*)d_in[1];
    const float* bjx = (const float*)d_in[2];
    const float* Wjh = (const float*)d_in[3];
    const float* bjh = (const float*)d_in[4];
    const float* Wkx = (const float*)d_in[5];
    const float* bkx = (const float*)d_in[6];
    const float* Wkh = (const float*)d_in[7];
    const float* bkh = (const float*)d_in[8];
    float* out = (float*)d_out;

    char* ws = (char*)d_ws;
    float* ring = (float*)ws;                    // RING*B*H*4 = 1,048,576 B
    int*   ctr  = (int*)(ws + 1048576);          // 2*512*4 lines * 64 B = 262,144 B

    hipMemsetAsync(ctr, 0, 262144, stream);

    void* args[] = { (void*)&x, (void*)&Wjx, (void*)&bjx, (void*)&Wjh, (void*)&bjh,
                     (void*)&Wkx, (void*)&bkx, (void*)&Wkh, (void*)&bkh,
                     (void*)&out, (void*)&ring, (void*)&ctr };
    hipLaunchCooperativeKernel((void*)rnn_persistent, dim3(256), dim3(256),
                               args, 0, stream);
}

// Round 5
// 4791.476 us; speedup vs baseline: 3.6938x; 1.2929x over previous
//
#include <hip/hip_runtime.h>
#include <hip/hip_bf16.h>
#include <type_traits>

// FF_27650999451977: 2-layer gated RNN (MGU), SEQ=512, B=64, H=IN=512, FP32 I/O.
// Persistent cooperative kernel, flag-based pipeline sync.
// Round-5 change: NO acquire fence (the per-step buffer_inv L2-invalidation
// storm was the dominant cost). Dynamic data (h state: ring / out history) is
// read with agent-scope relaxed atomic loads (sc0 sc1 -> read straight from
// the LLC coherence point, where producers' write-through stores land).
// Static x keeps plain cached loads and now stays warm in L2.

#define SEQn 512
#define Bn   64
#define Hn   512
#define RING 8    // layer-0 h-history ring depth (back-pressured)

typedef __bf16 bf16x8 __attribute__((ext_vector_type(8)));
typedef float  f32x4  __attribute__((ext_vector_type(4)));

// counter index: [layer][t][mg] -> 64B-padded lines (16 ints)
__device__ __forceinline__ int cidx(int l, int t, int mg) {
    return ((((l << 9) | t) << 2) | mg) << 4;
}

__device__ __forceinline__ void spin_until(const int* p, int target) {
    while (__hip_atomic_load(p, __ATOMIC_RELAXED, __HIP_MEMORY_SCOPE_AGENT) < target)
        __builtin_amdgcn_s_sleep(1);
}

// cached (L1/L2) fp32 -> bf16 x8
__device__ __forceinline__ bf16x8 cvt8(const float* p) {
    bf16x8 r;
#pragma unroll
    for (int i = 0; i < 8; ++i) r[i] = (__bf16)p[i];
    return r;
}
// coherent (LLC-direct) fp32 -> bf16 x8
__device__ __forceinline__ bf16x8 cvt8c(const float* p) {
    bf16x8 r;
#pragma unroll
    for (int i = 0; i < 8; ++i) {
        float f = __hip_atomic_load(p + i, __ATOMIC_RELAXED, __HIP_MEMORY_SCOPE_AGENT);
        r[i] = (__bf16)f;
    }
    return r;
}

__global__ void __launch_bounds__(256, 1)
rnn_persistent(const float* __restrict__ x,
               const float* __restrict__ Wjx, const float* __restrict__ bjx,
               const float* __restrict__ Wjh, const float* __restrict__ bjh,
               const float* __restrict__ Wkx, const float* __restrict__ bkx,
               const float* __restrict__ Wkh, const float* __restrict__ bkh,
               float* __restrict__ out,       // [SEQ][B][H] outputs, then [2][B][H] hidden
               float* __restrict__ ring,      // ws: [RING][B][H] layer-0 h history ring
               int* __restrict__ ctr)         // ws: counters
{
    const int wg    = blockIdx.x;
    const int layer = wg >> 7;       // 0..1
    const int id    = wg & 127;
    const int mg    = id >> 5;       // 0..3  (16 batch rows each)
    const int ng    = id & 31;       // 0..31 (16 output units each)
    const int tid   = threadIdx.x;
    const int wave  = tid >> 6;      // 0..3  (K-split: waves 0,1 = x-side, 2,3 = h-side)
    const int lane  = tid & 63;

    // ---- stationary weights -> bf16 VGPR frags (B-operand: col = lane&15) ----
    const int ucol = ng * 16 + (lane & 15);
    const int koff = (wave & 1) * 256 + ((lane >> 4) << 3);  // k offset within 512-half
    const float* wjsrc = ((wave < 2) ? Wjx : Wjh) + (size_t)layer * Hn * Hn + (size_t)ucol * Hn + koff;
    const float* wksrc = ((wave < 2) ? Wkx : Wkh) + (size_t)layer * Hn * Hn + (size_t)ucol * Hn + koff;
    bf16x8 wj[8], wk[8];
#pragma unroll
    for (int kt = 0; kt < 8; ++kt) {
        wj[kt] = cvt8(wjsrc + kt * 32);
        wk[kt] = cvt8(wksrc + kt * 32);
    }

    // ---- epilogue constants: thread tid -> output (row ml, unit nu) ----
    const int ml = tid >> 4;             // 0..15
    const int nu = tid & 15;             // 0..15
    const int ue = ng * 16 + nu;         // global unit
    const int be = mg * 16 + ml;         // global batch row
    const float bje = bjx[layer * Hn + ue] + bjh[layer * Hn + ue];
    const float bke = bkx[layer * Hn + ue] + bkh[layer * Hn + ue];

    __shared__ float part[4][2][16][16];  // [wave][j/k][row][col]

    const int m = mg * 16 + (lane & 15);  // A row (batch) for MFMA fragments

    auto compute_store = [&](const float* Abase, auto coh_tag) {
        constexpr bool COH = decltype(coh_tag)::value;
        f32x4 aj = {0.f, 0.f, 0.f, 0.f}, ak = {0.f, 0.f, 0.f, 0.f};
        const float* arow = Abase + (size_t)m * Hn + koff;
#pragma unroll
        for (int kt = 0; kt < 8; ++kt) {
            bf16x8 af;
            if constexpr (COH) af = cvt8c(arow + kt * 32);
            else               af = cvt8(arow + kt * 32);
            aj = __builtin_amdgcn_mfma_f32_16x16x32_bf16(af, wj[kt], aj, 0, 0, 0);
            ak = __builtin_amdgcn_mfma_f32_16x16x32_bf16(af, wk[kt], ak, 0, 0, 0);
        }
#pragma unroll
        for (int r = 0; r < 4; ++r) {
            part[wave][0][((lane >> 4) << 2) + r][lane & 15] = aj[r];
            part[wave][1][((lane >> 4) << 2) + r][lane & 15] = ak[r];
        }
    };
    auto zero_store = [&]() {
#pragma unroll
        for (int r = 0; r < 4; ++r) {
            part[wave][0][((lane >> 4) << 2) + r][lane & 15] = 0.f;
            part[wave][1][((lane >> 4) << 2) + r][lane & 15] = 0.f;
        }
    };

    for (int t = 0; t < SEQn; ++t) {
        const int slot  = t & (RING - 1);
        const int pslot = (t - 1) & (RING - 1);
        const float *Ax, *Ah;
        float* hc;
        if (layer == 0) {
            Ax = x + (size_t)t * Bn * Hn;
            Ah = ring + (size_t)pslot * Bn * Hn;                    // valid only if t>0
            hc = ring + (size_t)slot * Bn * Hn;
        } else {
            Ax = ring + (size_t)slot * Bn * Hn;                     // layer-0 output, step t
            Ah = (t > 0) ? (out + (size_t)(t - 1) * Bn * Hn) : out; // deref'd only if t>0
            hc = out + (size_t)t * Bn * Hn;
        }

        // layer-0 x-side waves depend only on static input: compute before waiting
        const bool pre = (layer == 0) && (wave < 2);
        if (pre) compute_store(Ax, std::false_type{});

        if (tid == 0) {
            if (layer == 0) {
                if (t > 0)     spin_until(ctr + cidx(0, t - 1, mg), 32);
                if (t >= RING) spin_until(ctr + cidx(1, t - RING, mg), 32);  // ring back-pressure
            } else {
                spin_until(ctr + cidx(0, t, mg), 32);
                if (t > 0) spin_until(ctr + cidx(1, t - 1, mg), 32);
            }
        }
        __syncthreads();
        // NO acquire fence: dynamic reads below are LLC-coherent atomic loads.

        // hoist h_prev (LLC latency overlaps the MFMA phase below)
        float hprev = 0.f;
        if (t > 0)
            hprev = __hip_atomic_load(Ah + (size_t)be * Hn + ue,
                                      __ATOMIC_RELAXED, __HIP_MEMORY_SCOPE_AGENT);

        if (!pre) {
            if (layer == 1 && wave < 2) compute_store(Ax, std::true_type{});   // ring: dynamic
            else if (wave < 2)          compute_store(Ax, std::false_type{});  // (unreachable; x static)
            else if (t > 0)             compute_store(Ah, std::true_type{});   // h history: dynamic
            else                        zero_store();
        }
        __syncthreads();

        // ---- epilogue: reduce K-split partials, gates, h update ----
        float sj = part[0][0][ml][nu] + part[1][0][ml][nu] +
                   part[2][0][ml][nu] + part[3][0][ml][nu] + bje;
        float sk = part[0][1][ml][nu] + part[1][1][ml][nu] +
                   part[2][1][ml][nu] + part[3][1][ml][nu] + bke;
        float jj = 1.f / (1.f + __expf(-sj));
        float kk = 1.f / (1.f + __expf(-sk));
        float hnew = jj * (1.f - hprev) + (1.f - kk) * hprev;

        // write-through to the coherence point (LLC)
        __hip_atomic_store(hc + (size_t)be * Hn + ue, hnew,
                           __ATOMIC_RELAXED, __HIP_MEMORY_SCOPE_AGENT);
        if (t == SEQn - 1)
            out[(size_t)SEQn * Bn * Hn + (size_t)layer * Bn * Hn + (size_t)be * Hn + ue] = hnew;

        // __syncthreads drains vmcnt (stores acked at LLC) before tid0 publishes.
        __syncthreads();
        if (tid == 0)
            __hip_atomic_fetch_add(ctr + cidx(layer, t, mg), 1,
                                   __ATOMIC_RELAXED, __HIP_MEMORY_SCOPE_AGENT);
    }
}

extern "C" void kernel_launch(void* const* d_in, const int* in_sizes, int n_in,
                              void* d_out, int out_size, void* d_ws, size_t ws_size,
                              hipStream_t stream) {
    (void)in_sizes; (void)n_in; (void)out_size; (void)ws_size;

    const float* x   = (const float*)d_in[0];
    const float* Wjx = (const float*)d_in[1];
    const float* bjx = (const float*)d_in[2];
    const float* Wjh = (const float*)d_in[3];
    const float* bjh = (const float*)d_in[4];
    const float* Wkx = (const float*)d_in[5];
    const float* bkx = (const float*)d_in[6];
    const float* Wkh = (const float*)d_in[7];
    const float* bkh = (const float*)d_in[8];
    float* out = (float*)d_out;

    char* ws = (char*)d_ws;
    float* ring = (float*)ws;                    // RING*B*H*4 = 1,048,576 B
    int*   ctr  = (int*)(ws + 1048576);          // 2*512*4 lines * 64 B = 262,144 B

    hipMemsetAsync(ctr, 0, 262144, stream);

    void* args[] = { (void*)&x, (void*)&Wjx, (void*)&bjx, (void*)&Wjh, (void*)&bjh,
                     (void*)&Wkx, (void*)&bkx, (void*)&Wkh, (void*)&bkh,
                     (void*)&out, (void*)&ring, (void*)&ctr };
    hipLaunchCooperativeKernel((void*)rnn_persistent, dim3(256), dim3(256),
                               args, 0, stream);
}

// Round 7
// 4705.796 us; speedup vs baseline: 3.7611x; 1.0182x over previous
//
#include <hip/hip_runtime.h>
#include <hip/hip_bf16.h>

// FF_27650999451977: 2-layer gated RNN (MGU), SEQ=512, B=64, H=IN=512, FP32 I/O.
// Persistent cooperative kernel, flag-based pipeline sync.
// Round-7: round-6 design with LDS shrunk 72KB -> 40KB (bf16 tile staging).
// 72KB static LDS silently failed the cooperative launch (out stayed zero).
// Staging: coalesced 8B coherent loads -> cvt to bf16 -> swizzled LDS;
// MFMA fragments come straight from ds_read_b128 (no per-MFMA cvt).

#define SEQn 512
#define Bn   64
#define Hn   512
#define RING 8    // layer-0 output ring depth (back-pressured)

typedef __bf16 bf16x8 __attribute__((ext_vector_type(8)));
typedef float  f32x4  __attribute__((ext_vector_type(4)));
typedef unsigned long long u64;

// flag index: [layer][mg][ng] -> 64B lines (16 ints)
__device__ __forceinline__ int fidx(int l, int mg, int ng) {
    return ((((l << 2) | mg) << 5) | ng) << 4;
}

// cached fp32 -> bf16 x8 (static x path)
__device__ __forceinline__ bf16x8 cvt8(const float* p) {
    bf16x8 r;
#pragma unroll
    for (int i = 0; i < 8; ++i) r[i] = (__bf16)p[i];
    return r;
}

// Stage one contiguous [16 rows x 512 cols] fp32 tile into a swizzled bf16 LDS
// tile. Coherent (LLC-direct) 8-byte loads, consecutive lanes -> consecutive
// addresses. NTHR threads participate, tl in [0, NTHR).
template <int NTHR>
__device__ __forceinline__ void stage_tile(const float* __restrict__ src,
                                           char* __restrict__ dst, int tl) {
    constexpr int PAIRS = 4096 / NTHR;   // fp32-pairs per thread (16 or 32)
#pragma unroll
    for (int b = 0; b < PAIRS; ++b) {
        const int p = b * NTHR + tl;     // pair index (8B granules)
        u64 raw = __hip_atomic_load((const u64*)src + p,
                                    __ATOMIC_RELAXED, __HIP_MEMORY_SCOPE_AGENT);
        union { u64 u; float f[2]; } cv; cv.u = raw;
        union { __bf16 h[2]; unsigned u; } pk;
        pk.h[0] = (__bf16)cv.f[0];
        pk.h[1] = (__bf16)cv.f[1];
        const int r = p >> 8;            // row = (2p)/512
        *(unsigned*)(dst + ((p << 2) ^ ((r & 7) << 4))) = pk.u;
    }
}

__global__ void __launch_bounds__(256, 1)
rnn_persistent(const float* __restrict__ x,
               const float* __restrict__ Wjx, const float* __restrict__ bjx,
               const float* __restrict__ Wjh, const float* __restrict__ bjh,
               const float* __restrict__ Wkx, const float* __restrict__ bkx,
               const float* __restrict__ Wkh, const float* __restrict__ bkh,
               float* __restrict__ out,       // [SEQ][B][H] outputs, then [2][B][H] hidden
               float* __restrict__ ring,      // ws: [RING][B][H] layer-0 output ring
               int* __restrict__ flags)       // ws: per-producer flags
{
    const int wg    = blockIdx.x;
    const int layer = wg >> 7;       // 0..1
    const int id    = wg & 127;
    const int mg    = id >> 5;       // 0..3  (16 batch rows each)
    const int ng    = id & 31;       // 0..31 (16 output units each)
    const int tid   = threadIdx.x;
    const int wave  = tid >> 6;      // 0..3  (waves 0,1 = x-side, 2,3 = h-side)
    const int lane  = tid & 63;

    // ---- stationary weights -> bf16 VGPR frags (B-operand: col = lane&15) ----
    const int ucol = ng * 16 + (lane & 15);
    const int koff = (wave & 1) * 256 + ((lane >> 4) << 3);
    const float* wjsrc = ((wave < 2) ? Wjx : Wjh) + (size_t)layer * Hn * Hn + (size_t)ucol * Hn + koff;
    const float* wksrc = ((wave < 2) ? Wkx : Wkh) + (size_t)layer * Hn * Hn + (size_t)ucol * Hn + koff;
    bf16x8 wj[8], wk[8];
#pragma unroll
    for (int kt = 0; kt < 8; ++kt) {
        wj[kt] = cvt8(wjsrc + kt * 32);
        wk[kt] = cvt8(wksrc + kt * 32);
    }

    // ---- epilogue constants: thread tid -> output (row ml, unit nu) ----
    const int ml = tid >> 4;             // 0..15
    const int nu = tid & 15;             // 0..15
    const int ue = ng * 16 + nu;         // global unit
    const int be = mg * 16 + ml;         // global batch row
    const float bje = bjx[layer * Hn + ue] + bjh[layer * Hn + ue];
    const float bke = bkx[layer * Hn + ue] + bkh[layer * Hn + ue];

    __shared__ float part[4][2][16][16];   // 8 KB: [wave][j/k][row][col]
    __shared__ char  xT[16384];            // layer-1 input tile (bf16, swizzled)
    __shared__ char  hT[16384];            // own h(t-1) tile (bf16, swizzled)

    const int m = mg * 16 + (lane & 15);   // A row for MFMA fragments

    // x-side direct (cached) compute: layer-0 only
    auto compute_global = [&](const float* Abase) {
        f32x4 aj = {0.f, 0.f, 0.f, 0.f}, ak = {0.f, 0.f, 0.f, 0.f};
        const float* arow = Abase + (size_t)m * Hn + koff;
#pragma unroll
        for (int kt = 0; kt < 8; ++kt) {
            bf16x8 af = cvt8(arow + kt * 32);
            aj = __builtin_amdgcn_mfma_f32_16x16x32_bf16(af, wj[kt], aj, 0, 0, 0);
            ak = __builtin_amdgcn_mfma_f32_16x16x32_bf16(af, wk[kt], ak, 0, 0, 0);
        }
#pragma unroll
        for (int r = 0; r < 4; ++r) {
            part[wave][0][((lane >> 4) << 2) + r][lane & 15] = aj[r];
            part[wave][1][((lane >> 4) << 2) + r][lane & 15] = ak[r];
        }
    };
    // fragment compute from a staged, swizzled bf16 LDS tile
    auto compute_lds = [&](const char* tile) {
        f32x4 aj = {0.f, 0.f, 0.f, 0.f}, ak = {0.f, 0.f, 0.f, 0.f};
        const int r       = lane & 15;
        const int cb      = ((wave & 1) << 8) + ((lane >> 4) << 3);
        const int swz     = (r & 7) << 4;
        const int rowbase = r << 10;        // r * 512 cols * 2 B
#pragma unroll
        for (int kt = 0; kt < 8; ++kt) {
            const int c = cb + kt * 32;
            bf16x8 af = *(const bf16x8*)(tile + ((rowbase + (c << 1)) ^ swz));
            aj = __builtin_amdgcn_mfma_f32_16x16x32_bf16(af, wj[kt], aj, 0, 0, 0);
            ak = __builtin_amdgcn_mfma_f32_16x16x32_bf16(af, wk[kt], ak, 0, 0, 0);
        }
#pragma unroll
        for (int r2 = 0; r2 < 4; ++r2) {
            part[wave][0][((lane >> 4) << 2) + r2][lane & 15] = aj[r2];
            part[wave][1][((lane >> 4) << 2) + r2][lane & 15] = ak[r2];
        }
    };
    auto zero_store = [&]() {
#pragma unroll
        for (int r2 = 0; r2 < 4; ++r2) {
            part[wave][0][((lane >> 4) << 2) + r2][lane & 15] = 0.f;
            part[wave][1][((lane >> 4) << 2) + r2][lane & 15] = 0.f;
        }
    };

    for (int t = 0; t < SEQn; ++t) {
        const int slot  = t & (RING - 1);
        const int pslot = (t - 1) & (RING - 1);
        const float* hist = (layer == 0)
            ? ring + (size_t)pslot * Bn * Hn + (size_t)mg * 16 * Hn       // own h(t-1)
            : out  + (size_t)(t - 1) * Bn * Hn + (size_t)mg * 16 * Hn;    // own h(t-1)
        const float* xin  = ring + (size_t)slot * Bn * Hn + (size_t)mg * 16 * Hn; // layer-1 input
        float* hc = (layer == 0) ? ring + (size_t)slot * Bn * Hn
                                 : out  + (size_t)t * Bn * Hn;

        // layer-0 x-side: static input, compute before waiting
        if (layer == 0 && wave < 2)
            compute_global(x + (size_t)t * Bn * Hn);

        // ---- wait: wave 0 polls 64 flags (32 dep + 32 back-pressure/peer) ----
        if (wave == 0) {
            const int ng2 = lane & 31;
            const int* fp = flags + fidx(lane >> 5, mg, ng2);
            int tgt;
            if (layer == 0) tgt = (lane < 32) ? t : t - (RING - 1);   // L0 peers | L1 back-pressure
            else            tgt = (lane < 32) ? t + 1 : t;            // L0 input | L1 peers
            while (true) {
                int v = __hip_atomic_load(fp, __ATOMIC_RELAXED, __HIP_MEMORY_SCOPE_AGENT);
                if (__all(v >= tgt)) break;
                __builtin_amdgcn_s_sleep(1);
            }
        }
        __syncthreads();

        // hoist h_prev (exact fp32, one coherent dword/thread; latency hides
        // under the staging + MFMA phases below)
        float hprev = 0.f;
        if (t > 0)
            hprev = __hip_atomic_load(hist + ml * Hn + ue,
                                      __ATOMIC_RELAXED, __HIP_MEMORY_SCOPE_AGENT);

        // ---- stage dynamic tiles (coalesced coherent loads -> swizzled LDS) ----
        if (layer == 0) {
            if (t > 0) stage_tile<256>(hist, hT, tid);
        } else {
            if (wave < 2)   stage_tile<128>(xin, xT, tid);
            else if (t > 0) stage_tile<128>(hist, hT, tid - 128);
        }
        __syncthreads();

        // ---- fragment compute ----
        if (layer == 0) {
            if (wave >= 2) { if (t > 0) compute_lds(hT); else zero_store(); }
        } else {
            if (wave < 2) compute_lds(xT);
            else          { if (t > 0) compute_lds(hT); else zero_store(); }
        }
        __syncthreads();

        // ---- epilogue: reduce K-split partials, gates, h update ----
        float sj = part[0][0][ml][nu] + part[1][0][ml][nu] +
                   part[2][0][ml][nu] + part[3][0][ml][nu] + bje;
        float sk = part[0][1][ml][nu] + part[1][1][ml][nu] +
                   part[2][1][ml][nu] + part[3][1][ml][nu] + bke;
        float jj = 1.f / (1.f + __expf(-sj));
        float kk = 1.f / (1.f + __expf(-sk));
        float hnew = jj * (1.f - hprev) + (1.f - kk) * hprev;

        // write-through to the coherence point (LLC)
        __hip_atomic_store(hc + (size_t)be * Hn + ue, hnew,
                           __ATOMIC_RELAXED, __HIP_MEMORY_SCOPE_AGENT);
        if (t == SEQn - 1)
            out[(size_t)SEQn * Bn * Hn + (size_t)layer * Bn * Hn + (size_t)be * Hn + ue] = hnew;

        // __syncthreads drains vmcnt (h stores acked at LLC) before publish
        __syncthreads();
        if (tid == 0)
            __hip_atomic_store(flags + fidx(layer, mg, ng), t + 1,
                               __ATOMIC_RELAXED, __HIP_MEMORY_SCOPE_AGENT);
    }
}

extern "C" void kernel_launch(void* const* d_in, const int* in_sizes, int n_in,
                              void* d_out, int out_size, void* d_ws, size_t ws_size,
                              hipStream_t stream) {
    (void)in_sizes; (void)n_in; (void)out_size; (void)ws_size;

    const float* x   = (const float*)d_in[0];
    const float* Wjx = (const float*)d_in[1];
    const float* bjx = (const float*)d_in[2];
    const float* Wjh = (const float*)d_in[3];
    const float* bjh = (const float*)d_in[4];
    const float* Wkx = (const float*)d_in[5];
    const float* bkx = (const float*)d_in[6];
    const float* Wkh = (const float*)d_in[7];
    const float* bkh = (const float*)d_in[8];
    float* out = (float*)d_out;

    char* ws = (char*)d_ws;
    float* ring  = (float*)ws;                   // RING*B*H*4 = 1,048,576 B
    int*   flags = (int*)(ws + 1048576);         // 256 lines * 64 B = 16,384 B

    hipMemsetAsync(flags, 0, 16384, stream);

    void* args[] = { (void*)&x, (void*)&Wjx, (void*)&bjx, (void*)&Wjh, (void*)&bjh,
                     (void*)&Wkx, (void*)&bkx, (void*)&Wkh, (void*)&bkh,
                     (void*)&out, (void*)&ring, (void*)&flags };
    hipLaunchCooperativeKernel((void*)rnn_persistent, dim3(256), dim3(256),
                               args, 0, stream);
}

// Round 8
// 3404.509 us; speedup vs baseline: 5.1987x; 1.3822x over previous
//
#include <hip/hip_runtime.h>
#include <hip/hip_bf16.h>

// FF_27650999451977: 2-layer gated RNN (MGU), SEQ=512, B=64, H=IN=512, FP32 I/O.
// Persistent cooperative kernel, pipeline sync via aggregated per-cluster
// counters (8 hot lines device-wide; wave-coalesced single-dword polling).
// Round-8: (1) aggregated atomicAdd publish + 1-dword poll (kills the
// 64-line/WG poll storm that was congesting the LLC fabric); (2) staging as
// issue-all-loads -> one drain -> write-all-LDS (1 serial LLC RT per stage);
// (3) per-wave polling, no entry barrier (3 barriers/step).

#define SEQn 512
#define Bn   64
#define Hn   512
#define RING 8    // layer-0 output ring depth (back-pressured)

typedef __bf16 bf16x8 __attribute__((ext_vector_type(8)));
typedef float  f32x4  __attribute__((ext_vector_type(4)));
typedef unsigned long long u64;

// aggregated counter line: [layer][mg] -> 64B lines (16 ints)
__device__ __forceinline__ int cline(int l, int mg) { return ((l << 2) | mg) << 4; }

__device__ __forceinline__ int cload32(const int* p) {
    return __hip_atomic_load(p, __ATOMIC_RELAXED, __HIP_MEMORY_SCOPE_AGENT);
}
__device__ __forceinline__ u64 cload64(const u64* p) {
    return __hip_atomic_load(p, __ATOMIC_RELAXED, __HIP_MEMORY_SCOPE_AGENT);
}
__device__ __forceinline__ float cloadf(const float* p) {
    return __hip_atomic_load(p, __ATOMIC_RELAXED, __HIP_MEMORY_SCOPE_AGENT);
}

// cached fp32 -> bf16 x8 (static x path)
__device__ __forceinline__ bf16x8 cvt8(const float* p) {
    bf16x8 r;
#pragma unroll
    for (int i = 0; i < 8; ++i) r[i] = (__bf16)p[i];
    return r;
}

// convert one fp32 pair to packed bf16 and write to swizzled LDS tile
__device__ __forceinline__ void bfwrite(char* dst, int p, u64 raw) {
    union { u64 u; float f[2]; } cv; cv.u = raw;
    union { __bf16 h[2]; unsigned u; } pk;
    pk.h[0] = (__bf16)cv.f[0];
    pk.h[1] = (__bf16)cv.f[1];
    const int r = p >> 8;                 // 256 pairs (512 dwords) per row
    *(unsigned*)(dst + ((p << 2) ^ ((r & 7) << 4))) = pk.u;
}

__global__ void __launch_bounds__(256, 1)
rnn_persistent(const float* __restrict__ x,
               const float* __restrict__ Wjx, const float* __restrict__ bjx,
               const float* __restrict__ Wjh, const float* __restrict__ bjh,
               const float* __restrict__ Wkx, const float* __restrict__ bkx,
               const float* __restrict__ Wkh, const float* __restrict__ bkh,
               float* __restrict__ out,       // [SEQ][B][H] outputs, then [2][B][H] hidden
               float* __restrict__ ring,      // ws: [RING][B][H] layer-0 output ring
               int* __restrict__ ctr)         // ws: 8 aggregated counter lines
{
    const int wg    = blockIdx.x;
    const int layer = wg >> 7;       // 0..1
    const int id    = wg & 127;
    const int mg    = id >> 5;       // 0..3  (16 batch rows each)
    const int ng    = id & 31;       // 0..31 (16 output units each)
    const int tid   = threadIdx.x;
    const int wave  = tid >> 6;      // 0..3  (waves 0,1 = x-side, 2,3 = h-side)
    const int lane  = tid & 63;

    // ---- stationary weights -> bf16 VGPR frags (B-operand: col = lane&15) ----
    const int ucol = ng * 16 + (lane & 15);
    const int koff = (wave & 1) * 256 + ((lane >> 4) << 3);
    const float* wjsrc = ((wave < 2) ? Wjx : Wjh) + (size_t)layer * Hn * Hn + (size_t)ucol * Hn + koff;
    const float* wksrc = ((wave < 2) ? Wkx : Wkh) + (size_t)layer * Hn * Hn + (size_t)ucol * Hn + koff;
    bf16x8 wj[8], wk[8];
#pragma unroll
    for (int kt = 0; kt < 8; ++kt) {
        wj[kt] = cvt8(wjsrc + kt * 32);
        wk[kt] = cvt8(wksrc + kt * 32);
    }

    // ---- epilogue constants: thread tid -> output (row ml, unit nu) ----
    const int ml = tid >> 4;             // 0..15
    const int nu = tid & 15;             // 0..15
    const int ue = ng * 16 + nu;         // global unit
    const int be = mg * 16 + ml;         // global batch row
    const float bje = bjx[layer * Hn + ue] + bjh[layer * Hn + ue];
    const float bke = bkx[layer * Hn + ue] + bkh[layer * Hn + ue];

    __shared__ float part[4][2][16][16];   // 8 KB: [wave][j/k][row][col]
    __shared__ char  xT[16384];            // layer-1 input tile (bf16, swizzled)
    __shared__ char  hT[16384];            // own h(t-1) tile (bf16, swizzled)

    const int m = mg * 16 + (lane & 15);   // A row for MFMA fragments

    auto compute_global = [&](const float* Abase) {
        f32x4 aj = {0.f, 0.f, 0.f, 0.f}, ak = {0.f, 0.f, 0.f, 0.f};
        const float* arow = Abase + (size_t)m * Hn + koff;
#pragma unroll
        for (int kt = 0; kt < 8; ++kt) {
            bf16x8 af = cvt8(arow + kt * 32);
            aj = __builtin_amdgcn_mfma_f32_16x16x32_bf16(af, wj[kt], aj, 0, 0, 0);
            ak = __builtin_amdgcn_mfma_f32_16x16x32_bf16(af, wk[kt], ak, 0, 0, 0);
        }
#pragma unroll
        for (int r = 0; r < 4; ++r) {
            part[wave][0][((lane >> 4) << 2) + r][lane & 15] = aj[r];
            part[wave][1][((lane >> 4) << 2) + r][lane & 15] = ak[r];
        }
    };
    auto compute_lds = [&](const char* tile) {
        f32x4 aj = {0.f, 0.f, 0.f, 0.f}, ak = {0.f, 0.f, 0.f, 0.f};
        const int r       = lane & 15;
        const int cb      = ((wave & 1) << 8) + ((lane >> 4) << 3);
        const int swz     = (r & 7) << 4;
        const int rowbase = r << 10;        // r * 512 cols * 2 B
#pragma unroll
        for (int kt = 0; kt < 8; ++kt) {
            const int c = cb + kt * 32;
            bf16x8 af = *(const bf16x8*)(tile + ((rowbase + (c << 1)) ^ swz));
            aj = __builtin_amdgcn_mfma_f32_16x16x32_bf16(af, wj[kt], aj, 0, 0, 0);
            ak = __builtin_amdgcn_mfma_f32_16x16x32_bf16(af, wk[kt], ak, 0, 0, 0);
        }
#pragma unroll
        for (int r2 = 0; r2 < 4; ++r2) {
            part[wave][0][((lane >> 4) << 2) + r2][lane & 15] = aj[r2];
            part[wave][1][((lane >> 4) << 2) + r2][lane & 15] = ak[r2];
        }
    };
    auto zero_store = [&]() {
#pragma unroll
        for (int r2 = 0; r2 < 4; ++r2) {
            part[wave][0][((lane >> 4) << 2) + r2][lane & 15] = 0.f;
            part[wave][1][((lane >> 4) << 2) + r2][lane & 15] = 0.f;
        }
    };

    const int* c0 = ctr + cline(0, mg);
    const int* c1 = ctr + cline(1, mg);

    for (int t = 0; t < SEQn; ++t) {
        const int slot  = t & (RING - 1);
        const int pslot = (t - 1) & (RING - 1);
        const float* hist = (layer == 0)
            ? ring + (size_t)pslot * Bn * Hn + (size_t)mg * 16 * Hn       // own h(t-1)
            : out  + (size_t)(t - 1) * Bn * Hn + (size_t)mg * 16 * Hn;    // own h(t-1)
        const float* xin  = ring + (size_t)slot * Bn * Hn + (size_t)mg * 16 * Hn; // layer-1 input
        float* hc = (layer == 0) ? ring + (size_t)slot * Bn * Hn
                                 : out  + (size_t)t * Bn * Hn;

        // layer-0 x-side: static input, compute before waiting (part[] write is
        // safe: previous iteration's epilogue reads ended at barrier C)
        if (layer == 0 && wave < 2)
            compute_global(x + (size_t)t * Bn * Hn);

        // ---- wait: every thread polls the two cluster counters (uniform
        // address -> 1 coalesced request per wave per counter) ----
        {
            int tgt0, tgt1;
            if (layer == 0) { tgt0 = 32 * t;       tgt1 = 32 * (t - (RING - 1)); }
            else            { tgt0 = 32 * (t + 1); tgt1 = 32 * t; }
            while (cload32(c0) < tgt0 || cload32(c1) < tgt1)
                __builtin_amdgcn_s_sleep(1);
        }

        // hoist h_prev (exact fp32; latency hides under staging/MFMA)
        float hprev = 0.f;
        if (t > 0)
            hprev = cloadf(hist + ml * Hn + ue);

        // ---- stage dynamic tiles: issue ALL coherent loads, one drain,
        // then all LDS writes (single serial LLC round trip) ----
        if (layer == 0) {
            if (t > 0) {
                u64 buf[16];
#pragma unroll
                for (int b = 0; b < 16; ++b)
                    buf[b] = cload64((const u64*)hist + b * 256 + tid);
#pragma unroll
                for (int b = 0; b < 16; ++b)
                    bfwrite(hT, b * 256 + tid, buf[b]);
            }
        } else {
            u64 bx[16], bh[16];
#pragma unroll
            for (int b = 0; b < 16; ++b)
                bx[b] = cload64((const u64*)xin + b * 256 + tid);
            if (t > 0) {
#pragma unroll
                for (int b = 0; b < 16; ++b)
                    bh[b] = cload64((const u64*)hist + b * 256 + tid);
            }
#pragma unroll
            for (int b = 0; b < 16; ++b)
                bfwrite(xT, b * 256 + tid, bx[b]);
            if (t > 0) {
#pragma unroll
                for (int b = 0; b < 16; ++b)
                    bfwrite(hT, b * 256 + tid, bh[b]);
            }
        }
        __syncthreads();   // A: staged tiles visible

        // ---- fragment compute ----
        if (layer == 0) {
            if (wave >= 2) { if (t > 0) compute_lds(hT); else zero_store(); }
        } else {
            if (wave < 2) compute_lds(xT);
            else          { if (t > 0) compute_lds(hT); else zero_store(); }
        }
        __syncthreads();   // B: part[] complete

        // ---- epilogue: reduce K-split partials, gates, h update ----
        float sj = part[0][0][ml][nu] + part[1][0][ml][nu] +
                   part[2][0][ml][nu] + part[3][0][ml][nu] + bje;
        float sk = part[0][1][ml][nu] + part[1][1][ml][nu] +
                   part[2][1][ml][nu] + part[3][1][ml][nu] + bke;
        float jj = 1.f / (1.f + __expf(-sj));
        float kk = 1.f / (1.f + __expf(-sk));
        float hnew = jj * (1.f - hprev) + (1.f - kk) * hprev;

        // write-through to the coherence point (LLC)
        __hip_atomic_store(hc + (size_t)be * Hn + ue, hnew,
                           __ATOMIC_RELAXED, __HIP_MEMORY_SCOPE_AGENT);
        if (t == SEQn - 1)
            out[(size_t)SEQn * Bn * Hn + (size_t)layer * Bn * Hn + (size_t)be * Hn + ue] = hnew;

        __syncthreads();   // C: drains vmcnt -> h stores at LLC before publish
        if (tid == 0)
            __hip_atomic_fetch_add(ctr + cline(layer, mg), 1,
                                   __ATOMIC_RELAXED, __HIP_MEMORY_SCOPE_AGENT);
    }
}

extern "C" void kernel_launch(void* const* d_in, const int* in_sizes, int n_in,
                              void* d_out, int out_size, void* d_ws, size_t ws_size,
                              hipStream_t stream) {
    (void)in_sizes; (void)n_in; (void)out_size; (void)ws_size;

    const float* x   = (const float*)d_in[0];
    const float* Wjx = (const float*)d_in[1];
    const float* bjx = (const float*)d_in[2];
    const float* Wjh = (const float*)d_in[3];
    const float* bjh = (const float*)d_in[4];
    const float* Wkx = (const float*)d_in[5];
    const float* bkx = (const float*)d_in[6];
    const float* Wkh = (const float*)d_in[7];
    const float* bkh = (const float*)d_in[8];
    float* out = (float*)d_out;

    char* ws = (char*)d_ws;
    float* ring = (float*)ws;                   // RING*B*H*4 = 1,048,576 B
    int*   ctr  = (int*)(ws + 1048576);         // 8 lines * 64 B (pad to 4 KB)

    hipMemsetAsync(ctr, 0, 4096, stream);

    void* args[] = { (void*)&x, (void*)&Wjx, (void*)&bjx, (void*)&Wjh, (void*)&bjh,
                     (void*)&Wkx, (void*)&bkx, (void*)&Wkh, (void*)&bkh,
                     (void*)&out, (void*)&ring, (void*)&ctr };
    hipLaunchCooperativeKernel((void*)rnn_persistent, dim3(256), dim3(256),
                               args, 0, stream);
}

// Round 9
// 2763.498 us; speedup vs baseline: 6.4045x; 1.2320x over previous
//
#include <hip/hip_runtime.h>
#include <hip/hip_bf16.h>

// FF_27650999451977: 2-layer gated RNN (MGU), SEQ=512, B=64, H=IN=512, FP32 I/O.
// Persistent cooperative kernel. Round-9: STAMPED-DATA sync — h communicated as
// (bf16<<16 | step_stamp) words; consumers poll the data itself (publish,
// detect, transfer = ONE LLC round trip). h_prev lives in a register (exact).
// No counters, no atomicAdd, 3 barriers/step.

#define SEQn 512
#define Bn   64
#define Hn   512
#define RING 8

typedef __bf16 bf16x8 __attribute__((ext_vector_type(8)));
typedef float  f32x4  __attribute__((ext_vector_type(4)));
typedef unsigned u32;

__device__ __forceinline__ u32 cload(const u32* p) {
    return __hip_atomic_load(p, __ATOMIC_RELAXED, __HIP_MEMORY_SCOPE_AGENT);
}
__device__ __forceinline__ void cstore(u32* p, u32 v) {
    __hip_atomic_store(p, v, __ATOMIC_RELAXED, __HIP_MEMORY_SCOPE_AGENT);
}
__device__ __forceinline__ unsigned short f2bf(float f) {
    u32 u = __float_as_uint(f);
    u += 0x7FFFu + ((u >> 16) & 1u);   // round-to-nearest-even
    return (unsigned short)(u >> 16);
}
__device__ __forceinline__ bf16x8 cvt8(const float* p) {
    bf16x8 r;
#pragma unroll
    for (int i = 0; i < 8; ++i) r[i] = (__bf16)p[i];
    return r;
}

__global__ void __launch_bounds__(256, 1)
rnn_persistent(const float* __restrict__ x,
               const float* __restrict__ Wjx, const float* __restrict__ bjx,
               const float* __restrict__ Wjh, const float* __restrict__ bjh,
               const float* __restrict__ Wkx, const float* __restrict__ bkx,
               const float* __restrict__ Wkh, const float* __restrict__ bkh,
               float* __restrict__ out,   // [SEQ][B][H] outputs, then [2][B][H] hidden
               u32* __restrict__ ring0,   // ws: [RING][B][H] stamped L0 h
               u32* __restrict__ ring1,   // ws: [RING][B][H] stamped L1 h
               u32* __restrict__ flags)   // ws: [4][32] L1 staging progress
{
    const int wg    = blockIdx.x;
    const int layer = wg >> 7;       // 0..1
    const int id    = wg & 127;
    const int mg    = id >> 5;       // 0..3  (16 batch rows each)
    const int ng    = id & 31;       // 0..31 (16 output units each)
    const int tid   = threadIdx.x;
    const int wave  = tid >> 6;      // 0..3  (waves 0,1 = x-side, 2,3 = h-side)
    const int lane  = tid & 63;

    // ---- stationary weights -> bf16 VGPR frags (B-operand: col = lane&15) ----
    const int ucol = ng * 16 + (lane & 15);
    const int koff = (wave & 1) * 256 + ((lane >> 4) << 3);
    const float* wjsrc = ((wave < 2) ? Wjx : Wjh) + (size_t)layer * Hn * Hn + (size_t)ucol * Hn + koff;
    const float* wksrc = ((wave < 2) ? Wkx : Wkh) + (size_t)layer * Hn * Hn + (size_t)ucol * Hn + koff;
    bf16x8 wj[8], wk[8];
#pragma unroll
    for (int kt = 0; kt < 8; ++kt) {
        wj[kt] = cvt8(wjsrc + kt * 32);
        wk[kt] = cvt8(wksrc + kt * 32);
    }

    // ---- epilogue constants: thread tid -> output (row ml, unit nu) ----
    const int ml = tid >> 4;             // 0..15
    const int nu = tid & 15;             // 0..15
    const int ue = ng * 16 + nu;         // global unit
    const int be = mg * 16 + ml;         // global batch row
    const float bje = bjx[layer * Hn + ue] + bjh[layer * Hn + ue];
    const float bke = bkx[layer * Hn + ue] + bkh[layer * Hn + ue];

    __shared__ float part[4][2][16][16];   // 8 KB
    __shared__ char  xT[16384];            // layer-1 input tile (bf16, swizzled)
    __shared__ char  hT[16384];            // own h(t-1) tile (bf16, swizzled)

    const int m = mg * 16 + (lane & 15);   // A row for MFMA fragments

    auto compute_global = [&](const float* Abase) {
        f32x4 aj = {0.f, 0.f, 0.f, 0.f}, ak = {0.f, 0.f, 0.f, 0.f};
        const float* arow = Abase + (size_t)m * Hn + koff;
#pragma unroll
        for (int kt = 0; kt < 8; ++kt) {
            bf16x8 af = cvt8(arow + kt * 32);
            aj = __builtin_amdgcn_mfma_f32_16x16x32_bf16(af, wj[kt], aj, 0, 0, 0);
            ak = __builtin_amdgcn_mfma_f32_16x16x32_bf16(af, wk[kt], ak, 0, 0, 0);
        }
#pragma unroll
        for (int r = 0; r < 4; ++r) {
            part[wave][0][((lane >> 4) << 2) + r][lane & 15] = aj[r];
            part[wave][1][((lane >> 4) << 2) + r][lane & 15] = ak[r];
        }
    };
    auto compute_lds = [&](const char* tile) {
        f32x4 aj = {0.f, 0.f, 0.f, 0.f}, ak = {0.f, 0.f, 0.f, 0.f};
        const int r       = lane & 15;
        const int cb      = ((wave & 1) << 8) + ((lane >> 4) << 3);
        const int swz     = (r & 7) << 4;
        const int rowbase = r << 10;
#pragma unroll
        for (int kt = 0; kt < 8; ++kt) {
            const int c = cb + kt * 32;
            bf16x8 af = *(const bf16x8*)(tile + ((rowbase + (c << 1)) ^ swz));
            aj = __builtin_amdgcn_mfma_f32_16x16x32_bf16(af, wj[kt], aj, 0, 0, 0);
            ak = __builtin_amdgcn_mfma_f32_16x16x32_bf16(af, wk[kt], ak, 0, 0, 0);
        }
#pragma unroll
        for (int r2 = 0; r2 < 4; ++r2) {
            part[wave][0][((lane >> 4) << 2) + r2][lane & 15] = aj[r2];
            part[wave][1][((lane >> 4) << 2) + r2][lane & 15] = ak[r2];
        }
    };

    // poll a 16x512 stamped tile until every word carries `want`, then commit
    // the bf16 payloads into a swizzled LDS tile. All 256 threads, 32 words each.
    auto stage = [&](const u32* src, char* dstT, int want) {
        u32 v[32];
        const u32 w = (u32)want;
        while (true) {
            bool ok = true;
#pragma unroll
            for (int b = 0; b < 32; ++b) v[b] = cload(src + (b << 8) + tid);
#pragma unroll
            for (int b = 0; b < 32; ++b) ok &= ((v[b] & 0xFFFFu) == w);
            if (__all(ok)) break;
            __builtin_amdgcn_s_sleep(1);
        }
#pragma unroll
        for (int b = 0; b < 32; ++b) {
            const int d = (b << 8) + tid;
            const int r = d >> 9;
            *(unsigned short*)(dstT + ((d << 1) ^ ((r & 7) << 4))) = (unsigned short)(v[b] >> 16);
        }
    };

    float hprev = 0.f;   // this thread's own h(be,ue) — exact fp32, in register

    for (int t = 0; t < SEQn; ++t) {
        const int slot  = t & (RING - 1);
        const int pslot = (t - 1) & (RING - 1);
        const u32* hsrc = (layer == 0 ? ring0 : ring1)
                          + (size_t)pslot * Bn * Hn + (size_t)mg * 16 * Hn;
        const u32* xsrc = ring0 + (size_t)slot * Bn * Hn + (size_t)mg * 16 * Hn;

        // layer-0 x-side: static input, compute before the wait (fills spin time)
        if (layer == 0 && wave < 2)
            compute_global(x + (size_t)t * Bn * Hn);

        // ---- staging: stamped-data poll (+ fused ring back-pressure for L0) ----
        if (layer == 0) {
            u32 v[32];
            const u32 w = (u32)t;
            bool fok = (t < RING);
            const int fwant = t - RING + 1;
            while (true) {
                bool ok = true;
                if (!fok) {
                    int fv = (int)cload(flags + (mg << 5) + (lane & 31));
                    fok = __all(fv >= fwant);
                }
#pragma unroll
                for (int b = 0; b < 32; ++b) v[b] = cload(hsrc + (b << 8) + tid);
#pragma unroll
                for (int b = 0; b < 32; ++b) ok &= ((v[b] & 0xFFFFu) == w);
                if (fok && __all(ok)) break;
                __builtin_amdgcn_s_sleep(1);
            }
#pragma unroll
            for (int b = 0; b < 32; ++b) {
                const int d = (b << 8) + tid;
                const int r = d >> 9;
                *(unsigned short*)(hT + ((d << 1) ^ ((r & 7) << 4))) = (unsigned short)(v[b] >> 16);
            }
        } else {
            stage(hsrc, hT, t);       // own history: old data, exits instantly
            stage(xsrc, xT, t + 1);   // fresh layer-0 output: the real wait
        }
        __syncthreads();   // A: tiles staged

        // L1 publishes staging progress (gates L0's ring0 overwrite, RING back)
        if (layer == 1 && tid == 0)
            cstore(flags + (mg << 5) + ng, (u32)(t + 1));

        // ---- fragment compute ----
        if (layer == 0) { if (wave >= 2) compute_lds(hT); }
        else            { if (wave < 2) compute_lds(xT); else compute_lds(hT); }
        __syncthreads();   // B: part[] complete

        // ---- epilogue ----
        float sj = part[0][0][ml][nu] + part[1][0][ml][nu] +
                   part[2][0][ml][nu] + part[3][0][ml][nu] + bje;
        float sk = part[0][1][ml][nu] + part[1][1][ml][nu] +
                   part[2][1][ml][nu] + part[3][1][ml][nu] + bke;
        float jj = 1.f / (1.f + __expf(-sj));
        float kk = 1.f / (1.f + __expf(-sk));
        float hnew = jj * (1.f - hprev) + (1.f - kk) * hprev;
        hprev = hnew;

        // self-publishing stamped store (write-through to LLC)
        u32 word = ((u32)f2bf(hnew) << 16) | (u32)(t + 1);
        cstore((layer == 0 ? ring0 : ring1) + (size_t)slot * Bn * Hn + (size_t)be * Hn + ue, word);

        if (layer == 1)
            out[(size_t)t * Bn * Hn + (size_t)be * Hn + ue] = hnew;
        if (t == SEQn - 1)
            out[(size_t)SEQn * Bn * Hn + (size_t)layer * Bn * Hn + (size_t)be * Hn + ue] = hnew;

        __syncthreads();   // C: part[]/tiles safe for next iteration
    }
}

extern "C" void kernel_launch(void* const* d_in, const int* in_sizes, int n_in,
                              void* d_out, int out_size, void* d_ws, size_t ws_size,
                              hipStream_t stream) {
    (void)in_sizes; (void)n_in; (void)out_size; (void)ws_size;

    const float* x   = (const float*)d_in[0];
    const float* Wjx = (const float*)d_in[1];
    const float* bjx = (const float*)d_in[2];
    const float* Wjh = (const float*)d_in[3];
    const float* bjh = (const float*)d_in[4];
    const float* Wkx = (const float*)d_in[5];
    const float* bkx = (const float*)d_in[6];
    const float* Wkh = (const float*)d_in[7];
    const float* bkh = (const float*)d_in[8];
    float* out = (float*)d_out;

    char* ws = (char*)d_ws;
    u32* ring0 = (u32*)ws;                       // RING*B*H*4 = 1,048,576 B
    u32* ring1 = (u32*)(ws + 1048576);           // 1,048,576 B
    u32* flags = (u32*)(ws + 2097152);           // 512 B (pad to 4 KB)

    // zero stamps + flags every launch (also resets state between graph replays)
    hipMemsetAsync(ws, 0, 2097152 + 4096, stream);

    void* args[] = { (void*)&x, (void*)&Wjx, (void*)&bjx, (void*)&Wjh, (void*)&bjh,
                     (void*)&Wkx, (void*)&bkx, (void*)&Wkh, (void*)&bkh,
                     (void*)&out, (void*)&ring0, (void*)&ring1, (void*)&flags };
    hipLaunchCooperativeKernel((void*)rnn_persistent, dim3(256), dim3(256),
                               args, 0, stream);
}